// Round 8
// baseline (442.629 us; speedup 1.0000x reference)
//
#include <hip/hip_runtime.h>
#include <hip/hip_bf16.h>
#include <stdint.h>

#define N_NODES  50000
#define N_GRAPHS 256
#define DIM      128
#define N_EDGES  800000
#define K2       256            // fused K = [agg | h]
#define N_STRIPS (N_NODES / 16) // 3125, exact
#define PAD_CAP  64             // max degree slack (mean 16; fixed edge list, no overflow)
#define NPASS    4              // source-range passes; 12.8MB/4 = 3.2MB fits 4MB XCD L2
#define RANGE    12500          // N_NODES / NPASS

typedef __attribute__((ext_vector_type(8))) short  short8;
typedef __attribute__((ext_vector_type(4))) float  floatx4;
typedef __attribute__((ext_vector_type(4))) int    intx4;

__device__ __forceinline__ ushort f2bf(float f) {
    union { float f; uint32_t u; } c; c.f = f;
    uint32_t u = c.u;
    return (ushort)((u + 0x7fffu + ((u >> 16) & 1u)) >> 16);  // RNE
}

// ---------- fused prep: convert_x | prep_w | gbounds | cnt-zero | out-zero ----------
#define MB_CONV 6250
#define MB_PREPW (MB_CONV + 384)
#define MB_GB   (MB_PREPW + 196)
#define MB_CNT  (MB_GB + 196)
#define MB_OUT  (MB_CNT + 256)
__global__ __launch_bounds__(256) void k_misc(const float* __restrict__ x, ushort* __restrict__ xb,
                                              const float* __restrict__ Wl0, const float* __restrict__ Wr0,
                                              const float* __restrict__ Wl1, const float* __restrict__ Wr1,
                                              const float* __restrict__ Wl2, const float* __restrict__ Wr2,
                                              ushort* __restrict__ Wt,
                                              const int* __restrict__ batch,
                                              int* __restrict__ gstart, int* __restrict__ gend,
                                              int* __restrict__ cnt, float* __restrict__ out) {
    int b = blockIdx.x, t = threadIdx.x;
    if (b < MB_CONV) {                       // fp32 x -> bf16 (float4 granularity)
        int i = b * 256 + t;                 // i < 1.6M exactly
        float4 v = ((const float4*)x)[i];
        uint32_t lo = (uint32_t)f2bf(v.x) | ((uint32_t)f2bf(v.y) << 16);
        uint32_t hi = (uint32_t)f2bf(v.z) | ((uint32_t)f2bf(v.w) << 16);
        ((uint2*)xb)[i] = make_uint2(lo, hi);
    } else if (b < MB_PREPW) {               // Wt[l][n][k] = bf16(k<128 ? Wl[k][n] : Wr[k-128][n])
        int i = (b - MB_CONV) * 256 + t;     // i < 98304 exactly
        int layer = i / (DIM * K2);
        int j = i % (DIM * K2);
        int n = j / K2, k = j % K2;
        const float* Wl = (layer == 0) ? Wl0 : (layer == 1) ? Wl1 : Wl2;
        const float* Wr = (layer == 0) ? Wr0 : (layer == 1) ? Wr1 : Wr2;
        float v = (k < DIM) ? Wl[k * DIM + n] : Wr[(k - DIM) * DIM + n];
        Wt[i] = f2bf(v);
    } else if (b < MB_GB) {                  // per-graph node ranges from sorted batch
        int i = (b - MB_PREPW) * 256 + t;
        if (i < N_NODES) {
            int g = batch[i];
            if (i == 0) gstart[g] = 0;
            int gn = (i + 1 < N_NODES) ? batch[i + 1] : -1;
            if (gn != g) {
                gend[g] = i + 1;
                if (gn >= 0) gstart[gn] = i + 1;
            }
        }
    } else if (b < MB_CNT) {                 // zero degree counters (pre-build)
        int i = (b - MB_GB) * 256 + t;
        if (i < N_NODES) cnt[i] = 0;
    } else {                                 // zero output (pre-readout atomics)
        int i = (b - MB_CNT) * 256 + t;
        if (i < N_GRAPHS * 2 * DIM) out[i] = 0.f;
    }
}

// ---------- direct adjacency build: one kernel, global atomics ----------
__global__ __launch_bounds__(256) void k_build_direct(const int* __restrict__ src,
                                                      const int* __restrict__ dst,
                                                      int* __restrict__ cnt,
                                                      int* __restrict__ padded) {
    int i = blockIdx.x * 256 + threadIdx.x;
    if (i < N_EDGES) {
        int d = dst[i], s = src[i];
        int p = atomicAdd(&cnt[d], 1);
        if (p < PAD_CAP) __builtin_nontemporal_store(s, &padded[(size_t)d * PAD_CAP + p]);
    }
}

// ---------- fused SAGE layer with RANGE-PARTITIONED (L2-resident) gather ----------
// Lists are ascending (MODE 0 sorts + writes back), so each node's neighbors in source
// range p = [p*RANGE,(p+1)*RANGE) are one contiguous segment; boundaries via 3 ballot
// popcounts. Chunks are emitted PASS-MAJOR: every resident wave processes range 0's
// segments first, then range 1's, ... so each XCD's 4MB L2 holds the active 3.2MB h
// window and gathers hit L2 (~150cy) instead of L3 (~500-900cy). Per-node partials
// accumulate in an 8KB LDS f32 buffer (wave-local RMW per chunk; pass-major interleaves
// nodes so registers can't hold them). That buffer is dead before MFMA -> MODE 2 reuses
// it as the f32 readout tile. Gather pipeline: R5's proven register double-buffer.
// MODE 0: +in-wave bitonic sort + canonical writeback. MODE 1: plain. MODE 2: +readout.
template <int MODE>
__global__ __launch_bounds__(256) void k_layer(const ushort* __restrict__ h_in,
                                               int* __restrict__ padded,
                                               const int* __restrict__ cnt,
                                               const ushort* __restrict__ Wt,
                                               const float* __restrict__ bias,
                                               ushort* __restrict__ out_bf,
                                               const int* __restrict__ batch,
                                               float* __restrict__ gout) {
    __shared__ ushort sAgg[16 * DIM];              // 4 KB bf16 agg tile
    __shared__ int    sIdx[16 * PAD_CAP];          // 4 KB neighbor lists
    __shared__ float2 sAcc[16 * 64];               // 8 KB f32 accumulators [node][lane]
    __shared__ int    sCnt[16];
    __shared__ int    sChl[4][28];                 // chunks: q | (e0<<8) | (end<<16)
    __shared__ int    sGb[(MODE == 2) ? 16 : 1];   // per-row graph ids (MODE 2)

    int t    = threadIdx.x;
    int wid  = t >> 6;
    int lane = t & 63;
    int r0   = blockIdx.x * 16;
    const uint32_t* hw = (const uint32_t*)h_in;    // 64 dwords per row

    // ---- stage neighbor lists + degrees (coalesced, nontemporal) ----
    ((intx4*)sIdx)[t] = __builtin_nontemporal_load(
        ((const intx4*)(padded + (size_t)r0 * PAD_CAP)) + t);
    if (t < 16) sCnt[t] = cnt[r0 + t];
    if (MODE == 2 && t >= 16 && t < 32) sGb[t - 16] = batch[r0 + t - 16];
    // zero this wave's 4 accumulator rows (wave-local; no barrier needed)
    #pragma unroll
    for (int q = 0; q < 4; ++q)
        sAcc[(wid * 4 + q) * 64 + lane] = make_float2(0.f, 0.f);
    __syncthreads();

    // ---- MODE 0: canonicalize lists in-wave (4 sequential 64-lane bitonics) ----
    if (MODE == 0) {
        #pragma unroll
        for (int q = 0; q < 4; ++q) {
            int nl  = wid * 4 + q;
            int m   = min(sCnt[nl], PAD_CAP);
            int* lst = sIdx + nl * PAD_CAP;
            int v = (lane < m) ? lst[lane] : 0x7fffffff;   // pads sort to the end
            #pragma unroll
            for (int k = 2; k <= 64; k <<= 1) {
                #pragma unroll
                for (int j = k >> 1; j > 0; j >>= 1) {
                    int other  = __shfl_xor(v, j, 64);
                    bool down  = (lane & k) != 0;
                    bool lower = (lane & j) == 0;
                    v = (lower ^ down) ? min(v, other) : max(v, other);
                }
            }
            if (lane < m) {
                lst[lane] = v;                             // wave-local LDS, no barrier
                __builtin_nontemporal_store(v,             // canonical list for layers 1-2
                    &padded[(size_t)(r0 + nl) * PAD_CAP + lane]);
            }
        }
    }

    // ---- segment boundaries per node via ballot popcount (lists sorted) ----
    int ee[4][NPASS + 1];
    #pragma unroll
    for (int q = 0; q < 4; ++q) {
        int node = wid * 4 + q;
        int m = min(sCnt[node], PAD_CAP);
        int vq = (lane < m) ? sIdx[node * PAD_CAP + lane] : 0x7fffffff;
        ee[q][0] = 0;
        ee[q][NPASS] = m;
        #pragma unroll
        for (int p = 1; p < NPASS; ++p)
            ee[q][p] = (int)__popcll(__ballot(vq < p * RANGE));
    }
    // ---- PASS-MAJOR chunk list (lane 0 writes; uniform counter) ----
    int nch = 0;
    #pragma unroll
    for (int p = 0; p < NPASS; ++p) {
        #pragma unroll
        for (int q = 0; q < 4; ++q) {
            int e0 = ee[q][p], e1 = ee[q][p + 1];
            for (; e0 < e1; e0 += 16) {                    // uniform runtime loop
                if (lane == 0) sChl[wid][nch] = q | (e0 << 8) | (e1 << 16);
                ++nch;
            }
        }
    }

    uint32_t va[16], vb[16];                       // double-buffered gather rows

    auto issue = [&](int ci, uint32_t (&v)[16]) {
        int ch  = sChl[wid][ci];
        int q   = ch & 15, e0 = (ch >> 8) & 255, end = ch >> 16;
        int node = wid * 4 + q;
        const int* lst = sIdx + node * PAD_CAP;
        #pragma unroll
        for (int k = 0; k < 16; ++k) {
            int ek = e0 + k;
            int id = lst[ek < end ? ek : end - 1]; // LDS broadcast; end>=1 for emitted chunks
            v[k] = hw[(size_t)id * 64 + lane];     // 16 row loads in flight
        }
    };
    auto consume = [&](int ci, uint32_t (&v)[16]) {
        int ch  = sChl[wid][ci];
        int q   = ch & 15, e0 = (ch >> 8) & 255, end = ch >> 16;
        int node = wid * 4 + q;
        float ax0 = 0.f, ax1 = 0.f, ay0 = 0.f, ay1 = 0.f;
        #pragma unroll
        for (int k = 0; k < 16; ++k) {
            uint32_t w = (e0 + k < end) ? v[k] : 0u;   // predicated tail (bf16 +0.0)
            if (k & 1) { ax1 += __uint_as_float(w << 16); ay1 += __uint_as_float(w & 0xffff0000u); }
            else       { ax0 += __uint_as_float(w << 16); ay0 += __uint_as_float(w & 0xffff0000u); }
        }
        float2* acc = &sAcc[node * 64 + lane];     // wave-local RMW (in-order DS pipe)
        float2 c = *acc;
        c.x += ax0 + ax1; c.y += ay0 + ay1;
        *acc = c;
    };

    if (nch > 0) {
        issue(0, va);
        int i = 0;
        while (true) {
            bool hasB = (i + 1) < nch;
            if (hasB) issue(i + 1, vb);            // overlap: loads(i+1) || accumulate(i)
            consume(i, va);
            if (!hasB) break;
            bool hasA = (i + 2) < nch;
            if (hasA) issue(i + 2, va);
            consume(i + 1, vb);
            if (!hasA) break;
            i += 2;
        }
    }
    // ---- finalize this wave's 4 nodes: mean + bf16 pack into sAgg ----
    #pragma unroll
    for (int q = 0; q < 4; ++q) {
        int node = wid * 4 + q;
        int deg  = sCnt[node];
        float inv = 1.0f / (float)(deg > 0 ? deg : 1);
        float2 c = sAcc[node * 64 + lane];
        uint32_t o = (uint32_t)f2bf(c.x * inv) | ((uint32_t)f2bf(c.y * inv) << 16);
        ((uint32_t*)(sAgg + node * DIM))[lane] = o;
    }
    __syncthreads();                               // all sAcc dead from here on

    // ---- phase 2: MFMA. A-frags: lane holds A[m=lane&15][k=quad*8+j] ----
    float* hTile = (float*)sAcc;                   // reuse 8 KB as f32 out tile (MODE 2)
    int row  = lane & 15;
    int quad = lane >> 4;
    short8 a[8];
    const ushort* srow = sAgg + row * DIM + quad * 8;
    #pragma unroll
    for (int ks = 0; ks < 4; ++ks) a[ks] = *(const short8*)(srow + ks * 32);  // LDS b128
    const ushort* hrow = h_in + (size_t)(r0 + row) * DIM + quad * 8;
    #pragma unroll
    for (int ks = 0; ks < 4; ++ks) a[4 + ks] = *(const short8*)(hrow + ks * 32);

    #pragma unroll
    for (int c = 0; c < 2; ++c) {
        int ct  = wid * 2 + c;                     // 4 waves x 2 = 8 col-tiles
        int col = ct * 16 + row;
        const ushort* wrow = Wt + (size_t)col * K2 + quad * 8;
        floatx4 acc = {0.f, 0.f, 0.f, 0.f};
        #pragma unroll
        for (int ks = 0; ks < 8; ++ks) {
            short8 b = *(const short8*)(wrow + ks * 32);
            acc = __builtin_amdgcn_mfma_f32_16x16x32_bf16(a[ks], b, acc, 0, 0, 0);
        }
        float bv = bias[col];
        #pragma unroll
        for (int r = 0; r < 4; ++r) {
            int m = r0 + quad * 4 + r;             // C/D: col=lane&15, row=quad*4+reg
            float v = acc[r] + bv;
            v = v > 0.f ? v : 0.f;
            if (MODE < 2) __builtin_nontemporal_store(f2bf(v), &out_bf[(size_t)m * DIM + col]);
            else          hTile[(quad * 4 + r) * DIM + col] = v;
        }
    }

    // ---- MODE 2: in-block mean/max readout (batch sorted -> run-length flush) ----
    if (MODE == 2) {
        __syncthreads();
        int d     = t & 127;
        bool doMax = t >= 128;                     // threads 0-127: sum; 128-255: max
        float s = 0.f, mx = 0.f;
        int cur = sGb[0];
        #pragma unroll
        for (int m = 0; m < 16; ++m) {
            int g = sGb[m];
            if (g != cur) {
                if (doMax) atomicMax((int*)&gout[cur * 2 * DIM + DIM + d], __float_as_int(mx));
                else       atomicAdd(&gout[cur * 2 * DIM + d], s);
                cur = g; s = 0.f; mx = 0.f;
            }
            float v = hTile[m * DIM + d];
            s += v; mx = fmaxf(mx, v);
        }
        if (doMax) atomicMax((int*)&gout[cur * 2 * DIM + DIM + d], __float_as_int(mx));
        else       atomicAdd(&gout[cur * 2 * DIM + d], s);
    }
}

__global__ __launch_bounds__(256) void k_finalize(float* __restrict__ out,
                                                  const int* __restrict__ gstart,
                                                  const int* __restrict__ gend) {
    int i = blockIdx.x * 256 + threadIdx.x;
    if (i < N_GRAPHS * DIM) {
        int g = i / DIM, d = i % DIM;
        int c = gend[g] - gstart[g];
        out[g * 2 * DIM + d] /= (float)(c > 0 ? c : 1);
    }
}

extern "C" void kernel_launch(void* const* d_in, const int* in_sizes, int n_in,
                              void* d_out, int out_size, void* d_ws, size_t ws_size,
                              hipStream_t stream) {
    const float* x     = (const float*)d_in[0];
    const int*   ei    = (const int*)d_in[1];
    const int*   src   = ei;
    const int*   dst   = ei + N_EDGES;
    const int*   batch = (const int*)d_in[2];
    const float* Wl[3] = {(const float*)d_in[3], (const float*)d_in[6], (const float*)d_in[9]};
    const float* bl[3] = {(const float*)d_in[4], (const float*)d_in[7], (const float*)d_in[10]};
    const float* Wr[3] = {(const float*)d_in[5], (const float*)d_in[8], (const float*)d_in[11]};
    float* out = (float*)d_out;

    char* base = (char*)d_ws;
    size_t o = 0;
    auto alloc = [&](size_t b) -> char* {
        char* p = base + o;
        o = (o + b + 255) & ~(size_t)255;
        return p;
    };
    int*     gstart = (int*)alloc((size_t)N_GRAPHS * 4);
    int*     gend   = (int*)alloc((size_t)N_GRAPHS * 4);
    int*     cnt    = (int*)alloc((size_t)N_NODES * 4);
    int*     padded = (int*)alloc((size_t)N_NODES * PAD_CAP * 4);    // 12.8 MB
    ushort*  xb     = (ushort*)alloc((size_t)N_NODES * DIM * 2);
    ushort*  ha     = (ushort*)alloc((size_t)N_NODES * DIM * 2);
    ushort*  hb     = (ushort*)alloc((size_t)N_NODES * DIM * 2);
    ushort*  Wt     = (ushort*)alloc((size_t)3 * DIM * K2 * 2);
    (void)ws_size; (void)n_in; (void)in_sizes; (void)out_size;

    // 6 dispatches total
    k_misc<<<MB_OUT, 256, 0, stream>>>(x, xb, Wl[0], Wr[0], Wl[1], Wr[1], Wl[2], Wr[2],
                                       Wt, batch, gstart, gend, cnt, out);
    k_build_direct<<<(N_EDGES + 255) / 256, 256, 0, stream>>>(src, dst, cnt, padded);

    k_layer<0><<<N_STRIPS, 256, 0, stream>>>(xb, padded, cnt, Wt,                bl[0], ha, batch, out);
    k_layer<1><<<N_STRIPS, 256, 0, stream>>>(ha, padded, cnt, Wt + DIM * K2,     bl[1], hb, batch, out);
    k_layer<2><<<N_STRIPS, 256, 0, stream>>>(hb, padded, cnt, Wt + 2 * DIM * K2, bl[2], nullptr, batch, out);

    k_finalize<<<(N_GRAPHS * DIM + 255) / 256, 256, 0, stream>>>(out, gstart, gend);
}

// Round 9
// 372.501 us; speedup vs baseline: 1.1883x; 1.1883x over previous
//
#include <hip/hip_runtime.h>
#include <hip/hip_bf16.h>
#include <stdint.h>

#define N_NODES  50000
#define N_GRAPHS 256
#define DIM      128
#define N_EDGES  800000
#define K2       256            // fused K = [agg | h]
#define N_STRIPS (N_NODES / 16) // 3125, exact
#define PAD_CAP  64             // max degree slack (mean 16; fixed edge list, no overflow)

typedef __attribute__((ext_vector_type(8))) short  short8;
typedef __attribute__((ext_vector_type(4))) float  floatx4;
typedef __attribute__((ext_vector_type(2))) int    intx2;

__device__ __forceinline__ ushort f2bf(float f) {
    union { float f; uint32_t u; } c; c.f = f;
    uint32_t u = c.u;
    return (ushort)((u + 0x7fffu + ((u >> 16) & 1u)) >> 16);  // RNE
}

// ---------- fused prep: convert_x | prep_w | gbounds | cnt-zero | out-zero ----------
#define MB_CONV 6250
#define MB_PREPW (MB_CONV + 384)
#define MB_GB   (MB_PREPW + 196)
#define MB_CNT  (MB_GB + 196)
#define MB_OUT  (MB_CNT + 256)
__global__ __launch_bounds__(256) void k_misc(const float* __restrict__ x, ushort* __restrict__ xb,
                                              const float* __restrict__ Wl0, const float* __restrict__ Wr0,
                                              const float* __restrict__ Wl1, const float* __restrict__ Wr1,
                                              const float* __restrict__ Wl2, const float* __restrict__ Wr2,
                                              ushort* __restrict__ Wt,
                                              const int* __restrict__ batch,
                                              int* __restrict__ gstart, int* __restrict__ gend,
                                              int* __restrict__ cnt, float* __restrict__ out) {
    int b = blockIdx.x, t = threadIdx.x;
    if (b < MB_CONV) {                       // fp32 x -> bf16 (float4 granularity)
        int i = b * 256 + t;                 // i < 1.6M exactly
        float4 v = ((const float4*)x)[i];
        uint32_t lo = (uint32_t)f2bf(v.x) | ((uint32_t)f2bf(v.y) << 16);
        uint32_t hi = (uint32_t)f2bf(v.z) | ((uint32_t)f2bf(v.w) << 16);
        ((uint2*)xb)[i] = make_uint2(lo, hi);
    } else if (b < MB_PREPW) {               // Wt[l][n][k] = bf16(k<128 ? Wl[k][n] : Wr[k-128][n])
        int i = (b - MB_CONV) * 256 + t;     // i < 98304 exactly
        int layer = i / (DIM * K2);
        int j = i % (DIM * K2);
        int n = j / K2, k = j % K2;
        const float* Wl = (layer == 0) ? Wl0 : (layer == 1) ? Wl1 : Wl2;
        const float* Wr = (layer == 0) ? Wr0 : (layer == 1) ? Wr1 : Wr2;
        float v = (k < DIM) ? Wl[k * DIM + n] : Wr[(k - DIM) * DIM + n];
        Wt[i] = f2bf(v);
    } else if (b < MB_GB) {                  // per-graph node ranges from sorted batch
        int i = (b - MB_PREPW) * 256 + t;
        if (i < N_NODES) {
            int g = batch[i];
            if (i == 0) gstart[g] = 0;
            int gn = (i + 1 < N_NODES) ? batch[i + 1] : -1;
            if (gn != g) {
                gend[g] = i + 1;
                if (gn >= 0) gstart[gn] = i + 1;
            }
        }
    } else if (b < MB_CNT) {                 // zero degree counters (pre-build)
        int i = (b - MB_GB) * 256 + t;
        if (i < N_NODES) cnt[i] = 0;
    } else {                                 // zero output (pre-readout atomics)
        int i = (b - MB_CNT) * 256 + t;
        if (i < N_GRAPHS * 2 * DIM) out[i] = 0.f;
    }
}

// ---------- direct adjacency build: one kernel, global atomics ----------
// Insertion order is nondeterministic; k_layer<0> sorts each list before any use.
// Scatter write is nontemporal (random 4B writes; avoid RFO).
__global__ __launch_bounds__(256) void k_build_direct(const int* __restrict__ src,
                                                      const int* __restrict__ dst,
                                                      int* __restrict__ cnt,
                                                      int* __restrict__ padded) {
    int i = blockIdx.x * 256 + threadIdx.x;
    if (i < N_EDGES) {
        int d = dst[i], s = src[i];
        int p = atomicAdd(&cnt[d], 1);
        if (p < PAD_CAP) __builtin_nontemporal_store(s, &padded[(size_t)d * PAD_CAP + p]);
    }
}

// ---------- fused SAGE layer: R5 structure at 8 waves/block (512 thr, 2 nodes/wave) ----------
// Same algorithm as the proven 327us kernel; only the wave->node mapping changes:
// 8 waves share one 16-row strip, each wave gathers 2 nodes (register double-buffer,
// 16 row-loads in flight) -> 2x resident gather waves per CU if blocks/CU is the cap.
// Phase 2: 8 col-tiles over 8 waves (1 each). MODE 0: +in-wave bitonic sort + canonical
// writeback. MODE 1: plain bf16 out. MODE 2: LDS f32 tile + in-block mean/max readout.
template <int MODE>
__global__ __launch_bounds__(512) void k_layer(const ushort* __restrict__ h_in,
                                               int* __restrict__ padded,
                                               const int* __restrict__ cnt,
                                               const ushort* __restrict__ Wt,
                                               const float* __restrict__ bias,
                                               ushort* __restrict__ out_bf,
                                               const int* __restrict__ batch,
                                               float* __restrict__ gout) {
    __shared__ ushort sAgg[16 * DIM];              // 4 KB
    __shared__ int    sIdx[16 * PAD_CAP];          // 4 KB neighbor lists
    __shared__ int    sCnt[16];
    __shared__ int    sChl[8][9];                  // per-wave chunk list: q | (e0<<8)
    __shared__ int    sNch[8];
    __shared__ int    sGb[(MODE == 2) ? 16 : 1];   // per-row graph ids (MODE 2)
    __shared__ float  hTile[(MODE == 2) ? 16 * DIM : 1];  // 8 KB f32 out tile (MODE 2)

    int t    = threadIdx.x;
    int wid  = t >> 6;                             // 0..7
    int lane = t & 63;
    int r0   = blockIdx.x * 16;
    const uint32_t* hw = (const uint32_t*)h_in;    // 64 dwords per row

    // ---- stage neighbor lists + degrees (coalesced, nontemporal; 512 x int2 = 4 KB) ----
    ((intx2*)sIdx)[t] = __builtin_nontemporal_load(
        ((const intx2*)(padded + (size_t)r0 * PAD_CAP)) + t);
    if (t < 16) sCnt[t] = cnt[r0 + t];
    if (MODE == 2 && t >= 16 && t < 32) sGb[t - 16] = batch[r0 + t - 16];
    __syncthreads();

    // ---- MODE 0: canonicalize lists in-wave (2 sequential 64-lane bitonics) ----
    if (MODE == 0) {
        #pragma unroll
        for (int q = 0; q < 2; ++q) {
            int nl  = wid * 2 + q;
            int m   = min(sCnt[nl], PAD_CAP);
            int* lst = sIdx + nl * PAD_CAP;
            int v = (lane < m) ? lst[lane] : 0x7fffffff;   // pads sort to the end
            #pragma unroll
            for (int k = 2; k <= 64; k <<= 1) {
                #pragma unroll
                for (int j = k >> 1; j > 0; j >>= 1) {
                    int other  = __shfl_xor(v, j, 64);
                    bool down  = (lane & k) != 0;
                    bool lower = (lane & j) == 0;
                    v = (lower ^ down) ? min(v, other) : max(v, other);
                }
            }
            if (lane < m) {
                lst[lane] = v;                             // wave-local LDS, no barrier
                __builtin_nontemporal_store(v,             // canonical list for layers 1-2
                    &padded[(size_t)(r0 + nl) * PAD_CAP + lane]);
            }
        }
    }

    // ---- per-wave flattened chunk list (wave-uniform; lane 0 writes) ----
    if (lane == 0) {
        int n = 0;
        #pragma unroll
        for (int q = 0; q < 2; ++q) {
            int m = min(sCnt[wid * 2 + q], PAD_CAP);
            for (int e0 = 0; e0 < m; e0 += 16)
                sChl[wid][n++] = q | (e0 << 8);
        }
        sNch[wid] = n;
    }
    // zero agg rows for isolated nodes (no chunks emitted for them)
    #pragma unroll
    for (int q = 0; q < 2; ++q) {
        int node = wid * 2 + q;
        if (sCnt[node] == 0) ((uint32_t*)(sAgg + node * DIM))[lane] = 0u;
    }
    int nch = sNch[wid];

    float ax[4] = {0.f, 0.f, 0.f, 0.f};
    float ay[4] = {0.f, 0.f, 0.f, 0.f};
    uint32_t va[16], vb[16];                       // double-buffered gather rows

    auto issue = [&](int ci, uint32_t (&v)[16]) {
        int ch   = sChl[wid][ci];
        int q    = ch & 255, e0 = ch >> 8;
        int node = wid * 2 + q;
        int m    = min(sCnt[node], PAD_CAP);
        const int* lst = sIdx + node * PAD_CAP;
        #pragma unroll
        for (int k = 0; k < 16; ++k) {
            int ek = e0 + k;
            int id = lst[ek < m ? ek : m - 1];     // LDS broadcast; m>=1 here
            v[k] = hw[(size_t)id * 64 + lane];     // 16 row loads in flight
        }
    };
    auto consume = [&](int ci, uint32_t (&v)[16], bool isLast) {
        int ch   = sChl[wid][ci];
        int q    = ch & 255, e0 = ch >> 8;
        int node = wid * 2 + q;
        int deg  = sCnt[node];
        int m    = min(deg, PAD_CAP);
        #pragma unroll
        for (int k = 0; k < 16; ++k) {
            uint32_t w = (e0 + k < m) ? v[k] : 0u; // predicated tail (bf16 +0.0)
            ax[k & 3] += __uint_as_float(w << 16);
            ay[k & 3] += __uint_as_float(w & 0xffff0000u);
        }
        bool lastOfNode = isLast || ((sChl[wid][ci + 1] & 255) != q);
        if (lastOfNode) {
            float axs = (ax[0] + ax[1]) + (ax[2] + ax[3]);
            float ays = (ay[0] + ay[1]) + (ay[2] + ay[3]);
            float inv = 1.0f / (float)(deg > 0 ? deg : 1);
            uint32_t o = (uint32_t)f2bf(axs * inv) | ((uint32_t)f2bf(ays * inv) << 16);
            ((uint32_t*)(sAgg + node * DIM))[lane] = o;
            #pragma unroll
            for (int j = 0; j < 4; ++j) { ax[j] = 0.f; ay[j] = 0.f; }
        }
    };

    if (nch > 0) {
        issue(0, va);
        int i = 0;
        while (true) {
            bool hasB = (i + 1) < nch;
            if (hasB) issue(i + 1, vb);            // overlap: loads(i+1) || accumulate(i)
            consume(i, va, !hasB);
            if (!hasB) break;
            bool hasA = (i + 2) < nch;
            if (hasA) issue(i + 2, va);
            consume(i + 1, vb, !hasA);
            if (!hasA) break;
            i += 2;
        }
    }
    __syncthreads();

    // ---- phase 2: MFMA. A-frags: lane holds A[m=lane&15][k=quad*8+j] ----
    int row  = lane & 15;
    int quad = lane >> 4;
    short8 a[8];
    const ushort* srow = sAgg + row * DIM + quad * 8;
    #pragma unroll
    for (int ks = 0; ks < 4; ++ks) a[ks] = *(const short8*)(srow + ks * 32);  // LDS b128
    const ushort* hrow = h_in + (size_t)(r0 + row) * DIM + quad * 8;
    #pragma unroll
    for (int ks = 0; ks < 4; ++ks) a[4 + ks] = *(const short8*)(hrow + ks * 32);

    {
        int col = wid * 16 + row;                  // 8 waves x 1 = 8 col-tiles
        const ushort* wrow = Wt + (size_t)col * K2 + quad * 8;
        floatx4 acc = {0.f, 0.f, 0.f, 0.f};
        #pragma unroll
        for (int ks = 0; ks < 8; ++ks) {
            short8 b = *(const short8*)(wrow + ks * 32);
            acc = __builtin_amdgcn_mfma_f32_16x16x32_bf16(a[ks], b, acc, 0, 0, 0);
        }
        float bv = bias[col];
        #pragma unroll
        for (int r = 0; r < 4; ++r) {
            int m = r0 + quad * 4 + r;             // C/D: col=lane&15, row=quad*4+reg
            float v = acc[r] + bv;
            v = v > 0.f ? v : 0.f;
            if (MODE < 2) __builtin_nontemporal_store(f2bf(v), &out_bf[(size_t)m * DIM + col]);
            else          hTile[(quad * 4 + r) * DIM + col] = v;
        }
    }

    // ---- MODE 2: in-block mean/max readout (batch sorted -> run-length flush) ----
    if (MODE == 2) {
        __syncthreads();
        if (t < 256) {
            int d     = t & 127;
            bool doMax = t >= 128;                 // threads 0-127: sum; 128-255: max
            float s = 0.f, mx = 0.f;
            int cur = sGb[0];
            #pragma unroll
            for (int m = 0; m < 16; ++m) {
                int g = sGb[m];
                if (g != cur) {
                    if (doMax) atomicMax((int*)&gout[cur * 2 * DIM + DIM + d], __float_as_int(mx));
                    else       atomicAdd(&gout[cur * 2 * DIM + d], s);
                    cur = g; s = 0.f; mx = 0.f;
                }
                float v = hTile[m * DIM + d];
                s += v; mx = fmaxf(mx, v);
            }
            if (doMax) atomicMax((int*)&gout[cur * 2 * DIM + DIM + d], __float_as_int(mx));
            else       atomicAdd(&gout[cur * 2 * DIM + d], s);
        }
    }
}

__global__ __launch_bounds__(256) void k_finalize(float* __restrict__ out,
                                                  const int* __restrict__ gstart,
                                                  const int* __restrict__ gend) {
    int i = blockIdx.x * 256 + threadIdx.x;
    if (i < N_GRAPHS * DIM) {
        int g = i / DIM, d = i % DIM;
        int c = gend[g] - gstart[g];
        out[g * 2 * DIM + d] /= (float)(c > 0 ? c : 1);
    }
}

extern "C" void kernel_launch(void* const* d_in, const int* in_sizes, int n_in,
                              void* d_out, int out_size, void* d_ws, size_t ws_size,
                              hipStream_t stream) {
    const float* x     = (const float*)d_in[0];
    const int*   ei    = (const int*)d_in[1];
    const int*   src   = ei;
    const int*   dst   = ei + N_EDGES;
    const int*   batch = (const int*)d_in[2];
    const float* Wl[3] = {(const float*)d_in[3], (const float*)d_in[6], (const float*)d_in[9]};
    const float* bl[3] = {(const float*)d_in[4], (const float*)d_in[7], (const float*)d_in[10]};
    const float* Wr[3] = {(const float*)d_in[5], (const float*)d_in[8], (const float*)d_in[11]};
    float* out = (float*)d_out;

    char* base = (char*)d_ws;
    size_t o = 0;
    auto alloc = [&](size_t b) -> char* {
        char* p = base + o;
        o = (o + b + 255) & ~(size_t)255;
        return p;
    };
    int*     gstart = (int*)alloc((size_t)N_GRAPHS * 4);
    int*     gend   = (int*)alloc((size_t)N_GRAPHS * 4);
    int*     cnt    = (int*)alloc((size_t)N_NODES * 4);
    int*     padded = (int*)alloc((size_t)N_NODES * PAD_CAP * 4);    // 12.8 MB
    ushort*  xb     = (ushort*)alloc((size_t)N_NODES * DIM * 2);
    ushort*  ha     = (ushort*)alloc((size_t)N_NODES * DIM * 2);
    ushort*  hb     = (ushort*)alloc((size_t)N_NODES * DIM * 2);
    ushort*  Wt     = (ushort*)alloc((size_t)3 * DIM * K2 * 2);
    (void)ws_size; (void)n_in; (void)in_sizes; (void)out_size;

    // 6 dispatches total
    k_misc<<<MB_OUT, 256, 0, stream>>>(x, xb, Wl[0], Wr[0], Wl[1], Wr[1], Wl[2], Wr[2],
                                       Wt, batch, gstart, gend, cnt, out);
    k_build_direct<<<(N_EDGES + 255) / 256, 256, 0, stream>>>(src, dst, cnt, padded);

    k_layer<0><<<N_STRIPS, 512, 0, stream>>>(xb, padded, cnt, Wt,                bl[0], ha, batch, out);
    k_layer<1><<<N_STRIPS, 512, 0, stream>>>(ha, padded, cnt, Wt + DIM * K2,     bl[1], hb, batch, out);
    k_layer<2><<<N_STRIPS, 512, 0, stream>>>(hb, padded, cnt, Wt + 2 * DIM * K2, bl[2], nullptr, batch, out);

    k_finalize<<<(N_GRAPHS * DIM + 255) / 256, 256, 0, stream>>>(out, gstart, gend);
}

// Round 10
// 325.201 us; speedup vs baseline: 1.3611x; 1.1454x over previous
//
#include <hip/hip_runtime.h>
#include <hip/hip_bf16.h>
#include <stdint.h>

#define N_NODES  50000
#define N_GRAPHS 256
#define DIM      128
#define N_EDGES  800000
#define K2       256            // fused K = [agg | h]
#define N_STRIPS (N_NODES / 16) // 3125, exact
#define PAD_CAP  64             // max degree slack (mean 16; fixed edge list, no overflow)
#define AGG_LD   132            // sAgg row stride in ushorts (264B: 4-way instead of 16-way LDS conflict)

typedef __attribute__((ext_vector_type(8))) short  short8;
typedef __attribute__((ext_vector_type(4))) short  s4v;
typedef __attribute__((ext_vector_type(4))) float  floatx4;
typedef __attribute__((ext_vector_type(4))) int    intx4;

__device__ __forceinline__ ushort f2bf(float f) {
    union { float f; uint32_t u; } c; c.f = f;
    uint32_t u = c.u;
    return (ushort)((u + 0x7fffu + ((u >> 16) & 1u)) >> 16);  // RNE
}

// ---------- fused prep: convert_x | prep_w | gbounds | cnt-zero | out-zero ----------
#define MB_CONV 6250
#define MB_PREPW (MB_CONV + 384)
#define MB_GB   (MB_PREPW + 196)
#define MB_CNT  (MB_GB + 196)
#define MB_OUT  (MB_CNT + 256)
__global__ __launch_bounds__(256) void k_misc(const float* __restrict__ x, ushort* __restrict__ xb,
                                              const float* __restrict__ Wl0, const float* __restrict__ Wr0,
                                              const float* __restrict__ Wl1, const float* __restrict__ Wr1,
                                              const float* __restrict__ Wl2, const float* __restrict__ Wr2,
                                              ushort* __restrict__ Wt,
                                              const int* __restrict__ batch,
                                              int* __restrict__ gstart, int* __restrict__ gend,
                                              int* __restrict__ cnt, float* __restrict__ out) {
    int b = blockIdx.x, t = threadIdx.x;
    if (b < MB_CONV) {                       // fp32 x -> bf16 (float4 granularity)
        int i = b * 256 + t;                 // i < 1.6M exactly
        float4 v = ((const float4*)x)[i];
        uint32_t lo = (uint32_t)f2bf(v.x) | ((uint32_t)f2bf(v.y) << 16);
        uint32_t hi = (uint32_t)f2bf(v.z) | ((uint32_t)f2bf(v.w) << 16);
        ((uint2*)xb)[i] = make_uint2(lo, hi);
    } else if (b < MB_PREPW) {               // Wt[l][n][k] = bf16(k<128 ? Wl[k][n] : Wr[k-128][n])
        int i = (b - MB_CONV) * 256 + t;     // i < 98304 exactly
        int layer = i / (DIM * K2);
        int j = i % (DIM * K2);
        int n = j / K2, k = j % K2;
        const float* Wl = (layer == 0) ? Wl0 : (layer == 1) ? Wl1 : Wl2;
        const float* Wr = (layer == 0) ? Wr0 : (layer == 1) ? Wr1 : Wr2;
        float v = (k < DIM) ? Wl[k * DIM + n] : Wr[(k - DIM) * DIM + n];
        Wt[i] = f2bf(v);
    } else if (b < MB_GB) {                  // per-graph node ranges from sorted batch
        int i = (b - MB_PREPW) * 256 + t;
        if (i < N_NODES) {
            int g = batch[i];
            if (i == 0) gstart[g] = 0;
            int gn = (i + 1 < N_NODES) ? batch[i + 1] : -1;
            if (gn != g) {
                gend[g] = i + 1;
                if (gn >= 0) gstart[gn] = i + 1;
            }
        }
    } else if (b < MB_CNT) {                 // zero degree counters (pre-build)
        int i = (b - MB_GB) * 256 + t;
        if (i < N_NODES) cnt[i] = 0;
    } else {                                 // zero output (pre-readout atomics)
        int i = (b - MB_CNT) * 256 + t;
        if (i < N_GRAPHS * 2 * DIM) out[i] = 0.f;
    }
}

// ---------- direct adjacency build: one kernel, global atomics ----------
// Insertion order is nondeterministic; k_layer<0> sorts each list before any use.
// Plain (cached) scatter store: padded is 12.8MB and mostly L2-resident — let L2
// absorb the random 4B writes (nt could force line-granular write-through).
__global__ __launch_bounds__(256) void k_build_direct(const int* __restrict__ src,
                                                      const int* __restrict__ dst,
                                                      int* __restrict__ cnt,
                                                      int* __restrict__ padded) {
    int i = blockIdx.x * 256 + threadIdx.x;
    if (i < N_EDGES) {
        int d = dst[i], s = src[i];
        int p = atomicAdd(&cnt[d], 1);
        if (p < PAD_CAP) padded[(size_t)d * PAD_CAP + p] = s;
    }
}

// ---------- fused SAGE layer (best-measured config: 4 waves, 4 nodes/wave, 2-chunk dbuf) ----------
// MODE 0: in-wave bitonic sort of each list + canonical writeback for layers 1-2.
// MODE 1: plain middle layer (bf16 out). MODE 2: last layer; LDS f32 tile + in-block
// per-graph mean/max readout. sAgg rows padded to AGG_LD=132 ushorts and A-frags read
// as b64 pairs: the old 256B stride put all 16 lanes of a quad on one 16B slot
// (16-way conflict, the stable 1.4M SQ_LDS_BANK_CONFLICT); 132-stride is 4-way.
template <int MODE>
__global__ __launch_bounds__(256) void k_layer(const ushort* __restrict__ h_in,
                                               int* __restrict__ padded,
                                               const int* __restrict__ cnt,
                                               const ushort* __restrict__ Wt,
                                               const float* __restrict__ bias,
                                               ushort* __restrict__ out_bf,
                                               const int* __restrict__ batch,
                                               float* __restrict__ gout) {
    __shared__ ushort sAgg[16 * AGG_LD];           // 4.1 KB (padded stride)
    __shared__ int    sIdx[16 * PAD_CAP];          // 4 KB neighbor lists
    __shared__ int    sCnt[16];
    __shared__ int    sChl[4][17];                 // per-wave chunk list: q | (e0<<8)
    __shared__ int    sNch[4];
    __shared__ int    sGb[(MODE == 2) ? 16 : 1];   // per-row graph ids (MODE 2)
    __shared__ float  hTile[(MODE == 2) ? 16 * DIM : 1];  // 8 KB f32 out tile (MODE 2)

    int t    = threadIdx.x;
    int wid  = t >> 6;
    int lane = t & 63;
    int r0   = blockIdx.x * 16;
    const uint32_t* hw = (const uint32_t*)h_in;    // 64 dwords per row

    // ---- stage neighbor lists + degrees (coalesced) ----
    ((intx4*)sIdx)[t] = ((const intx4*)(padded + (size_t)r0 * PAD_CAP))[t];
    if (t < 16) sCnt[t] = cnt[r0 + t];
    if (MODE == 2 && t >= 16 && t < 32) sGb[t - 16] = batch[r0 + t - 16];
    __syncthreads();

    // ---- MODE 0: canonicalize lists in-wave (4 sequential 64-lane bitonics) ----
    if (MODE == 0) {
        #pragma unroll
        for (int q = 0; q < 4; ++q) {
            int nl  = wid * 4 + q;
            int m   = min(sCnt[nl], PAD_CAP);
            int* lst = sIdx + nl * PAD_CAP;
            int v = (lane < m) ? lst[lane] : 0x7fffffff;   // pads sort to the end
            #pragma unroll
            for (int k = 2; k <= 64; k <<= 1) {
                #pragma unroll
                for (int j = k >> 1; j > 0; j >>= 1) {
                    int other  = __shfl_xor(v, j, 64);
                    bool down  = (lane & k) != 0;
                    bool lower = (lane & j) == 0;
                    v = (lower ^ down) ? min(v, other) : max(v, other);
                }
            }
            if (lane < m) {
                lst[lane] = v;                             // wave-local LDS, no barrier
                padded[(size_t)(r0 + nl) * PAD_CAP + lane] = v;  // canonical for layers 1-2
            }
        }
    }

    // ---- per-wave flattened chunk list (wave-uniform; lane 0 writes) ----
    if (lane == 0) {
        int n = 0;
        #pragma unroll
        for (int q = 0; q < 4; ++q) {
            int m = min(sCnt[wid * 4 + q], PAD_CAP);
            for (int e0 = 0; e0 < m; e0 += 16)
                sChl[wid][n++] = q | (e0 << 8);
        }
        sNch[wid] = n;
    }
    // zero agg rows for isolated nodes (no chunks emitted for them)
    #pragma unroll
    for (int q = 0; q < 4; ++q) {
        int node = wid * 4 + q;
        if (sCnt[node] == 0) ((uint32_t*)(sAgg + node * AGG_LD))[lane] = 0u;
    }
    int nch = sNch[wid];

    float ax[4] = {0.f, 0.f, 0.f, 0.f};
    float ay[4] = {0.f, 0.f, 0.f, 0.f};
    uint32_t va[16], vb[16];                       // double-buffered gather rows

    auto issue = [&](int ci, uint32_t (&v)[16]) {
        int ch   = sChl[wid][ci];
        int q    = ch & 255, e0 = ch >> 8;
        int node = wid * 4 + q;
        int m    = min(sCnt[node], PAD_CAP);
        const int* lst = sIdx + node * PAD_CAP;
        #pragma unroll
        for (int k = 0; k < 16; ++k) {
            int ek = e0 + k;
            int id = lst[ek < m ? ek : m - 1];     // LDS broadcast; m>=1 here
            v[k] = hw[(size_t)id * 64 + lane];     // 16 row loads in flight
        }
    };
    auto consume = [&](int ci, uint32_t (&v)[16], bool isLast) {
        int ch   = sChl[wid][ci];
        int q    = ch & 255, e0 = ch >> 8;
        int node = wid * 4 + q;
        int deg  = sCnt[node];
        int m    = min(deg, PAD_CAP);
        #pragma unroll
        for (int k = 0; k < 16; ++k) {
            uint32_t w = (e0 + k < m) ? v[k] : 0u; // predicated tail (bf16 +0.0)
            ax[k & 3] += __uint_as_float(w << 16);
            ay[k & 3] += __uint_as_float(w & 0xffff0000u);
        }
        bool lastOfNode = isLast || ((sChl[wid][ci + 1] & 255) != q);
        if (lastOfNode) {
            float axs = (ax[0] + ax[1]) + (ax[2] + ax[3]);
            float ays = (ay[0] + ay[1]) + (ay[2] + ay[3]);
            float inv = 1.0f / (float)(deg > 0 ? deg : 1);
            uint32_t o = (uint32_t)f2bf(axs * inv) | ((uint32_t)f2bf(ays * inv) << 16);
            ((uint32_t*)(sAgg + node * AGG_LD))[lane] = o;
            #pragma unroll
            for (int j = 0; j < 4; ++j) { ax[j] = 0.f; ay[j] = 0.f; }
        }
    };

    if (nch > 0) {
        issue(0, va);
        int i = 0;
        while (true) {
            bool hasB = (i + 1) < nch;
            if (hasB) issue(i + 1, vb);            // overlap: loads(i+1) || accumulate(i)
            consume(i, va, !hasB);
            if (!hasB) break;
            bool hasA = (i + 2) < nch;
            if (hasA) issue(i + 2, va);
            consume(i + 1, vb, !hasA);
            if (!hasA) break;
            i += 2;
        }
    }
    __syncthreads();

    // ---- phase 2: MFMA. A-frags: lane holds A[m=lane&15][k=quad*8+j] ----
    int row  = lane & 15;
    int quad = lane >> 4;
    short8 a[8];
    const ushort* srow = sAgg + row * AGG_LD + quad * 8;   // 8B-aligned (264B row stride)
    #pragma unroll
    for (int ks = 0; ks < 4; ++ks) {               // 2x ds_read_b64 per frag (4-way max)
        s4v lo = *(const s4v*)(srow + ks * 32);
        s4v hi = *(const s4v*)(srow + ks * 32 + 4);
        short8 v = {lo[0], lo[1], lo[2], lo[3], hi[0], hi[1], hi[2], hi[3]};
        a[ks] = v;
    }
    const ushort* hrow = h_in + (size_t)(r0 + row) * DIM + quad * 8;
    #pragma unroll
    for (int ks = 0; ks < 4; ++ks) a[4 + ks] = *(const short8*)(hrow + ks * 32);

    #pragma unroll
    for (int c = 0; c < 2; ++c) {
        int ct  = wid * 2 + c;                     // 4 waves x 2 = 8 col-tiles
        int col = ct * 16 + row;
        const ushort* wrow = Wt + (size_t)col * K2 + quad * 8;
        floatx4 acc = {0.f, 0.f, 0.f, 0.f};
        #pragma unroll
        for (int ks = 0; ks < 8; ++ks) {
            short8 b = *(const short8*)(wrow + ks * 32);
            acc = __builtin_amdgcn_mfma_f32_16x16x32_bf16(a[ks], b, acc, 0, 0, 0);
        }
        float bv = bias[col];
        #pragma unroll
        for (int r = 0; r < 4; ++r) {
            int m = r0 + quad * 4 + r;             // C/D: col=lane&15, row=quad*4+reg
            float v = acc[r] + bv;
            v = v > 0.f ? v : 0.f;
            if (MODE < 2) out_bf[(size_t)m * DIM + col] = f2bf(v);   // cached: next layer gathers it
            else          hTile[(quad * 4 + r) * DIM + col] = v;
        }
    }

    // ---- MODE 2: in-block mean/max readout (batch sorted -> run-length flush) ----
    if (MODE == 2) {
        __syncthreads();
        int d     = t & 127;
        bool doMax = t >= 128;                     // threads 0-127: sum; 128-255: max
        float s = 0.f, mx = 0.f;
        int cur = sGb[0];
        #pragma unroll
        for (int m = 0; m < 16; ++m) {
            int g = sGb[m];
            if (g != cur) {
                if (doMax) atomicMax((int*)&gout[cur * 2 * DIM + DIM + d], __float_as_int(mx));
                else       atomicAdd(&gout[cur * 2 * DIM + d], s);
                cur = g; s = 0.f; mx = 0.f;
            }
            float v = hTile[m * DIM + d];
            s += v; mx = fmaxf(mx, v);
        }
        if (doMax) atomicMax((int*)&gout[cur * 2 * DIM + DIM + d], __float_as_int(mx));
        else       atomicAdd(&gout[cur * 2 * DIM + d], s);
    }
}

__global__ __launch_bounds__(256) void k_finalize(float* __restrict__ out,
                                                  const int* __restrict__ gstart,
                                                  const int* __restrict__ gend) {
    int i = blockIdx.x * 256 + threadIdx.x;
    if (i < N_GRAPHS * DIM) {
        int g = i / DIM, d = i % DIM;
        int c = gend[g] - gstart[g];
        out[g * 2 * DIM + d] /= (float)(c > 0 ? c : 1);
    }
}

extern "C" void kernel_launch(void* const* d_in, const int* in_sizes, int n_in,
                              void* d_out, int out_size, void* d_ws, size_t ws_size,
                              hipStream_t stream) {
    const float* x     = (const float*)d_in[0];
    const int*   ei    = (const int*)d_in[1];
    const int*   src   = ei;
    const int*   dst   = ei + N_EDGES;
    const int*   batch = (const int*)d_in[2];
    const float* Wl[3] = {(const float*)d_in[3], (const float*)d_in[6], (const float*)d_in[9]};
    const float* bl[3] = {(const float*)d_in[4], (const float*)d_in[7], (const float*)d_in[10]};
    const float* Wr[3] = {(const float*)d_in[5], (const float*)d_in[8], (const float*)d_in[11]};
    float* out = (float*)d_out;

    char* base = (char*)d_ws;
    size_t o = 0;
    auto alloc = [&](size_t b) -> char* {
        char* p = base + o;
        o = (o + b + 255) & ~(size_t)255;
        return p;
    };
    int*     gstart = (int*)alloc((size_t)N_GRAPHS * 4);
    int*     gend   = (int*)alloc((size_t)N_GRAPHS * 4);
    int*     cnt    = (int*)alloc((size_t)N_NODES * 4);
    int*     padded = (int*)alloc((size_t)N_NODES * PAD_CAP * 4);    // 12.8 MB
    ushort*  xb     = (ushort*)alloc((size_t)N_NODES * DIM * 2);
    ushort*  ha     = (ushort*)alloc((size_t)N_NODES * DIM * 2);
    ushort*  hb     = (ushort*)alloc((size_t)N_NODES * DIM * 2);
    ushort*  Wt     = (ushort*)alloc((size_t)3 * DIM * K2 * 2);
    (void)ws_size; (void)n_in; (void)in_sizes; (void)out_size;

    // 6 dispatches total
    k_misc<<<MB_OUT, 256, 0, stream>>>(x, xb, Wl[0], Wr[0], Wl[1], Wr[1], Wl[2], Wr[2],
                                       Wt, batch, gstart, gend, cnt, out);
    k_build_direct<<<(N_EDGES + 255) / 256, 256, 0, stream>>>(src, dst, cnt, padded);

    k_layer<0><<<N_STRIPS, 256, 0, stream>>>(xb, padded, cnt, Wt,                bl[0], ha, batch, out);
    k_layer<1><<<N_STRIPS, 256, 0, stream>>>(ha, padded, cnt, Wt + DIM * K2,     bl[1], hb, batch, out);
    k_layer<2><<<N_STRIPS, 256, 0, stream>>>(hb, padded, cnt, Wt + 2 * DIM * K2, bl[2], nullptr, batch, out);

    k_finalize<<<(N_GRAPHS * DIM + 255) / 256, 256, 0, stream>>>(out, gstart, gend);
}